// Round 1
// baseline (430.666 us; speedup 1.0000x reference)
//
#include <hip/hip_runtime.h>
#include <stdint.h>
#include <math.h>

typedef unsigned short u16;
typedef unsigned int u32;
typedef __attribute__((ext_vector_type(8))) short bf16x8;
typedef __attribute__((ext_vector_type(4))) float f32x4;

#define SEQ 2048
#define HID 2048
#define NH  16
#define DH  128
#define NB  2

typedef __attribute__((address_space(1))) const u32 gu32;
typedef __attribute__((address_space(3))) u32 lu32;

__device__ __forceinline__ u16 f2bf(float f) {
  u32 u = __float_as_uint(f);
  return (u16)((u + 0x7fffu + ((u >> 16) & 1u)) >> 16);
}
__device__ __forceinline__ float bf2f(u16 h) { return __uint_as_float(((u32)h) << 16); }

__device__ __forceinline__ void gload_lds16(const void* g, void* l) {
  __builtin_amdgcn_global_load_lds((gu32*)g, (lu32*)l, 16, 0, 0);
}

// ---------------- fp32 -> bf16 convert ----------------
__global__ __launch_bounds__(256) void k_cvt(const float* __restrict__ src, u16* __restrict__ dst, int n4) {
  int i = blockIdx.x * 256 + threadIdx.x;
  int stride = gridDim.x * 256;
  for (; i < n4; i += stride) {
    float4 v = ((const float4*)src)[i];
    ushort4 o;
    o.x = f2bf(v.x); o.y = f2bf(v.y); o.z = f2bf(v.z); o.w = f2bf(v.w);
    ((ushort4*)dst)[i] = o;
  }
}

// ---------------- GEMM C = A * B^T  (A:[M,K], B:[N,K], bf16 in, fp32 acc) ----------------
// EPI=0: scatter qkv into Qr/Kr/Vr [B][H][L][D] bf16.  EPI=1: write float C[M,N].
template<int EPI>
__global__ __launch_bounds__(256)
void k_gemm(const u16* __restrict__ A, const u16* __restrict__ Bm,
            float* __restrict__ Cf, u16* __restrict__ Qr, u16* __restrict__ Kr, u16* __restrict__ Vr,
            int N, int K) {
  __shared__ alignas(16) char sA[128 * 128];
  __shared__ alignas(16) char sB[128 * 128];
  const int tid = threadIdx.x;
  const int wid = tid >> 6, lane = tid & 63;
  const int l15 = lane & 15, l4 = lane >> 4;
  const int m0 = blockIdx.y * 128, n0 = blockIdx.x * 128;
  const int wr = (wid >> 1) * 64, wc = (wid & 1) * 64;

  f32x4 acc[4][4];
  #pragma unroll
  for (int i = 0; i < 4; ++i)
    #pragma unroll
    for (int j = 0; j < 4; ++j)
      acc[i][j] = (f32x4){0.f, 0.f, 0.f, 0.f};

  const int nkt = K >> 6;
  for (int kt = 0; kt < nkt; ++kt) {
    const int k0 = kt << 6;
    __syncthreads();
    #pragma unroll
    for (int it = 0; it < 4; ++it) {
      int o = it * 4096 + tid * 16;
      int row = o >> 7, cb = o & 127;
      int scb = cb ^ ((row & 7) << 4);
      gload_lds16((const char*)A + ((size_t)(m0 + row) * K + k0) * 2 + scb, &sA[it * 4096 + wid * 1024]);
    }
    #pragma unroll
    for (int it = 0; it < 4; ++it) {
      int o = it * 4096 + tid * 16;
      int row = o >> 7, cb = o & 127;
      int scb = cb ^ ((row & 7) << 4);
      gload_lds16((const char*)Bm + ((size_t)(n0 + row) * K + k0) * 2 + scb, &sB[it * 4096 + wid * 1024]);
    }
    __syncthreads();
    #pragma unroll
    for (int kk = 0; kk < 2; ++kk) {
      bf16x8 av[4], bv[4];
      #pragma unroll
      for (int mi = 0; mi < 4; ++mi) {
        int row = wr + mi * 16 + l15;
        int colb = kk * 64 + 16 * l4;
        av[mi] = *(const bf16x8*)&sA[row * 128 + (colb ^ ((row & 7) << 4))];
      }
      #pragma unroll
      for (int ni = 0; ni < 4; ++ni) {
        int row = wc + ni * 16 + l15;
        int colb = kk * 64 + 16 * l4;
        bv[ni] = *(const bf16x8*)&sB[row * 128 + (colb ^ ((row & 7) << 4))];
      }
      #pragma unroll
      for (int mi = 0; mi < 4; ++mi)
        #pragma unroll
        for (int ni = 0; ni < 4; ++ni)
          acc[mi][ni] = __builtin_amdgcn_mfma_f32_16x16x32_bf16(av[mi], bv[ni], acc[mi][ni], 0, 0, 0);
    }
  }

  #pragma unroll
  for (int mi = 0; mi < 4; ++mi) {
    #pragma unroll
    for (int ni = 0; ni < 4; ++ni) {
      #pragma unroll
      for (int j = 0; j < 4; ++j) {
        int gm = m0 + wr + mi * 16 + l4 * 4 + j;
        int gn = n0 + wc + ni * 16 + l15;
        float v = acc[mi][ni][j];
        if (EPI == 0) {
          int b = gm >> 11, l = gm & 2047;
          int which = gn >> 11, hid = gn & 2047;
          int h = hid >> 7, d = hid & 127;
          u16* dst = (which == 0) ? Qr : ((which == 1) ? Kr : Vr);
          size_t idx = ((size_t)(b * NH + h) * SEQ + l) * DH + d;
          dst[idx] = f2bf(v);
        } else {
          Cf[(size_t)gm * N + gn] = v;
        }
      }
    }
  }
}

// ---------------- RMSNorm + interleaved RoPE, in place on [B*H*L][128] bf16 ----------------
__global__ __launch_bounds__(256) void k_nrope(u16* __restrict__ T) {
  const int r = blockIdx.x * 4 + (threadIdx.x >> 6);
  const int lane = threadIdx.x & 63;
  u16* p = T + ((size_t)r << 7) + lane * 2;
  u32 pr = *(const u32*)p;
  float xe = bf2f((u16)(pr & 0xffffu));  // x[2i]   (even)
  float xo = bf2f((u16)(pr >> 16));      // x[2i+1] (odd)
  float ss = xe * xe + xo * xo;
  #pragma unroll
  for (int off = 1; off < 64; off <<= 1) ss += __shfl_xor(ss, off);
  float rinv = rsqrtf(ss * (1.f / 128.f) + 1e-5f);
  float e = xe * rinv, o = xo * rinv;
  int pos = r & (SEQ - 1);
  // inv_freq[i] = 10000^(-2i/128) = exp2(-i * log2(10000)/64)
  float freq = exp2f(-0.20762050593046014f * (float)lane);
  float ang = (float)pos * freq;
  float sn, cs;
  sincosf(ang, &sn, &cs);
  // y[2i] = x_odd*cos - x_even*sin ; y[2i+1] = x_odd*sin + x_even*cos
  u32 outw = (u32)f2bf(o * cs - e * sn) | ((u32)f2bf(o * sn + e * cs) << 16);
  *(u32*)p = outw;
}

// ---------------- causal flash attention ----------------
// grid: B*H*(SEQ/64); block 256 = 4 waves, wave w owns 16 q rows.
__global__ __launch_bounds__(256) void k_attn(const u16* __restrict__ Q, const u16* __restrict__ Kg,
                                              const u16* __restrict__ V, u16* __restrict__ O) {
  __shared__ alignas(16) char sK[64 * 256];    // [64 kpos][128 d] bf16, XOR-swizzled rows (256B)
  __shared__ alignas(16) char sVt[128 * 144];  // [128 d][64 k + pad] bf16, 144B rows
  __shared__ alignas(16) char sP[4 * 16 * 144];// per-wave P [16 q][64 k + pad]
  const int tid = threadIdx.x, wid = tid >> 6, lane = tid & 63;
  const int l15 = lane & 15, l4 = lane >> 4;
  const int qt = blockIdx.x & 31;
  const int bh = blockIdx.x >> 5;
  const int b = bh >> 4, h = bh & 15;
  const u16* Qp = Q + ((size_t)bh << 18);
  const u16* Kp = Kg + ((size_t)bh << 18);
  const u16* Vp = V + ((size_t)bh << 18);
  const int qb = qt << 6;
  const int q0 = qb + wid * 16;

  bf16x8 aq[4];
  #pragma unroll
  for (int kk = 0; kk < 4; ++kk)
    aq[kk] = *(const bf16x8*)(Qp + (size_t)(q0 + l15) * DH + kk * 32 + 8 * l4);

  f32x4 accO[8];
  #pragma unroll
  for (int i = 0; i < 8; ++i) accO[i] = (f32x4){0.f, 0.f, 0.f, 0.f};
  float m_[4] = {-1e30f, -1e30f, -1e30f, -1e30f};
  float se[4] = {0.f, 0.f, 0.f, 0.f};
  const float scale = 0.08838834764831845f;  // 1/sqrt(128)

  const int nt = qt + 1;
  for (int t = 0; t < nt; ++t) {
    const int kb = t << 6;
    __syncthreads();
    // stage K tile [64][128] bf16, swizzled, via global_load_lds
    #pragma unroll
    for (int it = 0; it < 4; ++it) {
      int o = it * 4096 + tid * 16;
      int row = o >> 8, cb = o & 255;
      int scb = cb ^ ((row & 7) << 4);
      gload_lds16((const char*)Kp + ((size_t)(kb + row) << 8) + scb, &sK[it * 4096 + wid * 1024]);
    }
    // stage V transposed: sVt[d][k]
    {
      const int d = tid & 127;
      const int kb2 = (tid >> 7) << 3;
      #pragma unroll
      for (int pss = 0; pss < 4; ++pss) {
        int kloc = kb2 + pss * 16;
        bf16x8 vv;
        #pragma unroll
        for (int i = 0; i < 8; ++i)
          vv[i] = (short)Vp[(size_t)(kb + kloc + i) * DH + d];
        *(bf16x8*)&sVt[d * 144 + kloc * 2] = vv;
      }
    }
    __syncthreads();

    // S = Q K^T  (16 q x 64 k per wave)
    f32x4 sacc[4];
    #pragma unroll
    for (int sj = 0; sj < 4; ++sj) {
      sacc[sj] = (f32x4){0.f, 0.f, 0.f, 0.f};
      int row = sj * 16 + l15;
      #pragma unroll
      for (int kk = 0; kk < 4; ++kk) {
        int colb = kk * 64 + 16 * l4;
        bf16x8 bk = *(const bf16x8*)&sK[(row << 8) + (colb ^ ((row & 7) << 4))];
        sacc[sj] = __builtin_amdgcn_mfma_f32_16x16x32_bf16(aq[kk], bk, sacc[sj], 0, 0, 0);
      }
    }

    // online softmax
    float pvv[4][4], rm[4], rs[4], corr[4];
    #pragma unroll
    for (int j = 0; j < 4; ++j) {
      int qpos = q0 + l4 * 4 + j;
      float mx = -1e30f;
      #pragma unroll
      for (int sj = 0; sj < 4; ++sj) {
        int kpos = kb + sj * 16 + l15;
        float s = sacc[sj][j] * scale;
        s = (kpos > qpos) ? -1e30f : s;
        pvv[sj][j] = s;
        mx = fmaxf(mx, s);
      }
      rm[j] = mx;
    }
    #pragma unroll
    for (int off = 1; off < 16; off <<= 1) {
      #pragma unroll
      for (int j = 0; j < 4; ++j) rm[j] = fmaxf(rm[j], __shfl_xor(rm[j], off));
    }
    #pragma unroll
    for (int j = 0; j < 4; ++j) {
      float mn = fmaxf(m_[j], rm[j]);
      corr[j] = __expf(m_[j] - mn);
      m_[j] = mn;
      float sum = 0.f;
      #pragma unroll
      for (int sj = 0; sj < 4; ++sj) { float pe = __expf(pvv[sj][j] - mn); pvv[sj][j] = pe; sum += pe; }
      rs[j] = sum;
    }
    #pragma unroll
    for (int off = 1; off < 16; off <<= 1) {
      #pragma unroll
      for (int j = 0; j < 4; ++j) rs[j] += __shfl_xor(rs[j], off);
    }
    #pragma unroll
    for (int j = 0; j < 4; ++j) se[j] = se[j] * corr[j] + rs[j];
    #pragma unroll
    for (int db = 0; db < 8; ++db) {
      f32x4 a = accO[db];
      #pragma unroll
      for (int j = 0; j < 4; ++j) a[j] *= corr[j];
      accO[db] = a;
    }

    // P -> LDS (bf16)
    {
      u16* Pw = (u16*)(sP + wid * 2304);
      #pragma unroll
      for (int sj = 0; sj < 4; ++sj)
        #pragma unroll
        for (int j = 0; j < 4; ++j)
          Pw[(l4 * 4 + j) * 72 + sj * 16 + l15] = f2bf(pvv[sj][j]);
    }

    // O += P V
    bf16x8 pa0 = *(const bf16x8*)(sP + wid * 2304 + l15 * 144 + 16 * l4);
    bf16x8 pa1 = *(const bf16x8*)(sP + wid * 2304 + l15 * 144 + 16 * l4 + 64);
    #pragma unroll
    for (int db = 0; db < 8; ++db) {
      const char* vb = &sVt[(db * 16 + l15) * 144 + 16 * l4];
      accO[db] = __builtin_amdgcn_mfma_f32_16x16x32_bf16(pa0, *(const bf16x8*)vb, accO[db], 0, 0, 0);
      accO[db] = __builtin_amdgcn_mfma_f32_16x16x32_bf16(pa1, *(const bf16x8*)(vb + 64), accO[db], 0, 0, 0);
    }
  }

  // epilogue: O[b][q][h*128+d] bf16
  #pragma unroll
  for (int db = 0; db < 8; ++db) {
    #pragma unroll
    for (int j = 0; j < 4; ++j) {
      int q = q0 + l4 * 4 + j;
      int d = db * 16 + l15;
      float v = accO[db][j] / se[j];
      O[(size_t)(b * SEQ + q) * HID + h * DH + d] = f2bf(v);
    }
  }
}

extern "C" void kernel_launch(void* const* d_in, const int* in_sizes, int n_in,
                              void* d_out, int out_size, void* d_ws, size_t ws_size,
                              hipStream_t stream) {
  (void)in_sizes; (void)n_in; (void)out_size; (void)ws_size;
  const float* x = (const float*)d_in[0];
  const float* Wqkv = (const float*)d_in[1];
  const float* Wout = (const float*)d_in[2];
  float* out = (float*)d_out;
  char* ws = (char*)d_ws;

  u16* xb  = (u16*)(ws);                                   // 16 MB  [4096][2048] bf16
  u16* wqb = (u16*)(ws + (size_t)16777216);                // 24 MB  [6144][2048] bf16
  u16* wob = (u16*)(ws + (size_t)16777216 + 25165824);     // 8 MB   [2048][2048] bf16
  u16* Qr  = (u16*)(ws + (size_t)50331648);                // 16 MB  [B][H][L][D]
  u16* Kr  = Qr + (size_t)8388608;
  u16* Vr  = Kr + (size_t)8388608;
  u16* Ob  = xb;  // reuse x-bf16 region for attention output [4096][2048]

  k_cvt<<<dim3(1024), dim3(256), 0, stream>>>(x, xb, (NB * SEQ * HID) / 4);
  k_cvt<<<dim3(1024), dim3(256), 0, stream>>>(Wqkv, wqb, (3 * HID * HID) / 4);
  k_cvt<<<dim3(1024), dim3(256), 0, stream>>>(Wout, wob, (HID * HID) / 4);

  k_gemm<0><<<dim3(48, 32), dim3(256), 0, stream>>>(xb, wqb, nullptr, Qr, Kr, Vr, 3 * HID, HID);

  k_nrope<<<dim3((NB * NH * SEQ) / 4), dim3(256), 0, stream>>>(Qr);
  k_nrope<<<dim3((NB * NH * SEQ) / 4), dim3(256), 0, stream>>>(Kr);

  k_attn<<<dim3(NB * NH * (SEQ / 64)), dim3(256), 0, stream>>>(Qr, Kr, Vr, Ob);

  k_gemm<1><<<dim3(16, 32), dim3(256), 0, stream>>>(Ob, wob, out, nullptr, nullptr, nullptr, HID, HID);
}

// Round 3
// 428.981 us; speedup vs baseline: 1.0039x; 1.0039x over previous
//
#include <hip/hip_runtime.h>
#include <stdint.h>
#include <math.h>

typedef unsigned short u16;
typedef unsigned int u32;
typedef __attribute__((ext_vector_type(8))) short bf16x8;
typedef __attribute__((ext_vector_type(4))) float f32x4;

#define SEQ 2048
#define HID 2048
#define NH  16
#define DH  128
#define NB  2

typedef __attribute__((address_space(1))) const u32 gu32;
typedef __attribute__((address_space(3))) u32 lu32;

__device__ __forceinline__ u16 f2bf(float f) {
  u32 u = __float_as_uint(f);
  return (u16)((u + 0x7fffu + ((u >> 16) & 1u)) >> 16);
}
__device__ __forceinline__ float bf2f(u16 h) { return __uint_as_float(((u32)h) << 16); }

__device__ __forceinline__ void gload_lds16(const void* g, void* l) {
  __builtin_amdgcn_global_load_lds((gu32*)g, (lu32*)l, 16, 0, 0);
}

// ---------------- fp32 -> bf16 convert ----------------
__global__ __launch_bounds__(256) void k_cvt(const float* __restrict__ src, u16* __restrict__ dst, int n4) {
  int i = blockIdx.x * 256 + threadIdx.x;
  int stride = gridDim.x * 256;
  for (; i < n4; i += stride) {
    float4 v = ((const float4*)src)[i];
    ushort4 o;
    o.x = f2bf(v.x); o.y = f2bf(v.y); o.z = f2bf(v.z); o.w = f2bf(v.w);
    ((ushort4*)dst)[i] = o;
  }
}

// ---------------- GEMM C = A * B^T  (A:[M,K], B:[N,K], bf16 in, fp32 acc) ----------------
template<int EPI>
__global__ __launch_bounds__(256)
void k_gemm(const u16* __restrict__ A, const u16* __restrict__ Bm,
            float* __restrict__ Cf, u16* __restrict__ Qr, u16* __restrict__ Kr, u16* __restrict__ Vr,
            int N, int K) {
  __shared__ alignas(16) char sA[128 * 128];
  __shared__ alignas(16) char sB[128 * 128];
  const int tid = threadIdx.x;
  const int wid = tid >> 6, lane = tid & 63;
  const int l15 = lane & 15, l4 = lane >> 4;
  const int m0 = blockIdx.y * 128, n0 = blockIdx.x * 128;
  const int wr = (wid >> 1) * 64, wc = (wid & 1) * 64;

  f32x4 acc[4][4];
  #pragma unroll
  for (int i = 0; i < 4; ++i)
    #pragma unroll
    for (int j = 0; j < 4; ++j)
      acc[i][j] = (f32x4){0.f, 0.f, 0.f, 0.f};

  const int nkt = K >> 6;
  for (int kt = 0; kt < nkt; ++kt) {
    const int k0 = kt << 6;
    __syncthreads();
    #pragma unroll
    for (int it = 0; it < 4; ++it) {
      int o = it * 4096 + tid * 16;
      int row = o >> 7, cb = o & 127;
      int scb = cb ^ ((row & 7) << 4);
      gload_lds16((const char*)A + ((size_t)(m0 + row) * K + k0) * 2 + scb, &sA[it * 4096 + wid * 1024]);
    }
    #pragma unroll
    for (int it = 0; it < 4; ++it) {
      int o = it * 4096 + tid * 16;
      int row = o >> 7, cb = o & 127;
      int scb = cb ^ ((row & 7) << 4);
      gload_lds16((const char*)Bm + ((size_t)(n0 + row) * K + k0) * 2 + scb, &sB[it * 4096 + wid * 1024]);
    }
    __syncthreads();
    #pragma unroll
    for (int kk = 0; kk < 2; ++kk) {
      bf16x8 av[4], bv[4];
      #pragma unroll
      for (int mi = 0; mi < 4; ++mi) {
        int row = wr + mi * 16 + l15;
        int colb = kk * 64 + 16 * l4;
        av[mi] = *(const bf16x8*)&sA[row * 128 + (colb ^ ((row & 7) << 4))];
      }
      #pragma unroll
      for (int ni = 0; ni < 4; ++ni) {
        int row = wc + ni * 16 + l15;
        int colb = kk * 64 + 16 * l4;
        bv[ni] = *(const bf16x8*)&sB[row * 128 + (colb ^ ((row & 7) << 4))];
      }
      #pragma unroll
      for (int mi = 0; mi < 4; ++mi)
        #pragma unroll
        for (int ni = 0; ni < 4; ++ni)
          acc[mi][ni] = __builtin_amdgcn_mfma_f32_16x16x32_bf16(av[mi], bv[ni], acc[mi][ni], 0, 0, 0);
    }
  }

  #pragma unroll
  for (int mi = 0; mi < 4; ++mi) {
    #pragma unroll
    for (int ni = 0; ni < 4; ++ni) {
      #pragma unroll
      for (int j = 0; j < 4; ++j) {
        int gm = m0 + wr + mi * 16 + l4 * 4 + j;
        int gn = n0 + wc + ni * 16 + l15;
        float v = acc[mi][ni][j];
        if (EPI == 0) {
          int b = gm >> 11, l = gm & 2047;
          int which = gn >> 11, hid = gn & 2047;
          int h = hid >> 7, d = hid & 127;
          u16* dst = (which == 0) ? Qr : ((which == 1) ? Kr : Vr);
          size_t idx = ((size_t)(b * NH + h) * SEQ + l) * DH + d;
          dst[idx] = f2bf(v);
        } else {
          Cf[(size_t)gm * N + gn] = v;
        }
      }
    }
  }
}

// ---------------- V transpose: Vr[bh][l][d] -> Vt[bh][d][l] ----------------
__global__ __launch_bounds__(256) void k_vtr(const u16* __restrict__ Vr, u16* __restrict__ Vt) {
  __shared__ u16 tile[64][72];
  const int k0 = blockIdx.x * 64, d0 = blockIdx.y * 64, bh = blockIdx.z;
  const u16* src = Vr + ((size_t)bh << 18);
  u16* dst = Vt + ((size_t)bh << 18);
  const int tid = threadIdx.x;
  #pragma unroll
  for (int it = 0; it < 2; ++it) {
    int e = it * 2048 + tid * 8;
    int r = e >> 6, c = e & 63;
    bf16x8 v = *(const bf16x8*)(src + (size_t)(k0 + r) * DH + d0 + c);
    *(bf16x8*)&tile[r][c] = v;
  }
  __syncthreads();
  #pragma unroll
  for (int it = 0; it < 2; ++it) {
    int e = it * 2048 + tid * 8;
    int rd = e >> 6, ck = e & 63;
    bf16x8 w;
    #pragma unroll
    for (int i = 0; i < 8; ++i) w[i] = (short)tile[ck + i][rd];
    *(bf16x8*)(dst + (size_t)(d0 + rd) * SEQ + k0 + ck) = w;
  }
}

// ---------------- RMSNorm + interleaved RoPE, in place on [B*H*L][128] bf16 ----------------
__global__ __launch_bounds__(256) void k_nrope(u16* __restrict__ T) {
  const int r = blockIdx.x * 4 + (threadIdx.x >> 6);
  const int lane = threadIdx.x & 63;
  u16* p = T + ((size_t)r << 7) + lane * 2;
  u32 pr = *(const u32*)p;
  float xe = bf2f((u16)(pr & 0xffffu));
  float xo = bf2f((u16)(pr >> 16));
  float ss = xe * xe + xo * xo;
  #pragma unroll
  for (int off = 1; off < 64; off <<= 1) ss += __shfl_xor(ss, off);
  float rinv = rsqrtf(ss * (1.f / 128.f) + 1e-5f);
  float e = xe * rinv, o = xo * rinv;
  int pos = r & (SEQ - 1);
  float freq = exp2f(-0.20762050593046014f * (float)lane);
  float ang = (float)pos * freq;
  float sn, cs;
  sincosf(ang, &sn, &cs);
  u32 outw = (u32)f2bf(o * cs - e * sn) | ((u32)f2bf(o * sn + e * cs) << 16);
  *(u32*)p = outw;
}

// ---------------- causal flash attention, paired q-tiles ----------------
__device__ __forceinline__ void attn_tile(const char* sK, const char* sVt, char* sPw,
                                          const bf16x8* aq, f32x4* accO, float* m_, float* se,
                                          int q0, int kb, bool diag, int l15, int l4) {
  const float scale = 0.08838834764831845f;  // 1/sqrt(128)
  f32x4 sacc[4];
  #pragma unroll
  for (int sj = 0; sj < 4; ++sj) {
    sacc[sj] = (f32x4){0.f, 0.f, 0.f, 0.f};
    int row = sj * 16 + l15;
    #pragma unroll
    for (int kk = 0; kk < 4; ++kk) {
      int colb = kk * 64 + 16 * l4;
      bf16x8 bk = *(const bf16x8*)&sK[(row << 8) + (colb ^ ((row & 7) << 4))];
      sacc[sj] = __builtin_amdgcn_mfma_f32_16x16x32_bf16(aq[kk], bk, sacc[sj], 0, 0, 0);
    }
  }
  float pvv[4][4], rm[4], rs[4], corr[4];
  #pragma unroll
  for (int j = 0; j < 4; ++j) {
    int qpos = q0 + l4 * 4 + j;
    float mx = -1e30f;
    #pragma unroll
    for (int sj = 0; sj < 4; ++sj) {
      float s = sacc[sj][j] * scale;
      if (diag) {
        int kpos = kb + sj * 16 + l15;
        s = (kpos > qpos) ? -1e30f : s;
      }
      pvv[sj][j] = s;
      mx = fmaxf(mx, s);
    }
    rm[j] = mx;
  }
  #pragma unroll
  for (int off = 1; off < 16; off <<= 1) {
    #pragma unroll
    for (int j = 0; j < 4; ++j) rm[j] = fmaxf(rm[j], __shfl_xor(rm[j], off));
  }
  #pragma unroll
  for (int j = 0; j < 4; ++j) {
    float mn = fmaxf(m_[j], rm[j]);
    corr[j] = __expf(m_[j] - mn);
    m_[j] = mn;
    float sum = 0.f;
    #pragma unroll
    for (int sj = 0; sj < 4; ++sj) { float pe = __expf(pvv[sj][j] - mn); pvv[sj][j] = pe; sum += pe; }
    rs[j] = sum;
  }
  #pragma unroll
  for (int off = 1; off < 16; off <<= 1) {
    #pragma unroll
    for (int j = 0; j < 4; ++j) rs[j] += __shfl_xor(rs[j], off);
  }
  #pragma unroll
  for (int j = 0; j < 4; ++j) se[j] = se[j] * corr[j] + rs[j];
  #pragma unroll
  for (int db = 0; db < 8; ++db) {
    f32x4 a = accO[db];
    #pragma unroll
    for (int j = 0; j < 4; ++j) a[j] *= corr[j];
    accO[db] = a;
  }
  {
    u16* Pw = (u16*)sPw;
    #pragma unroll
    for (int sj = 0; sj < 4; ++sj)
      #pragma unroll
      for (int j = 0; j < 4; ++j)
        Pw[(l4 * 4 + j) * 72 + sj * 16 + l15] = f2bf(pvv[sj][j]);
  }
  bf16x8 pa0 = *(const bf16x8*)(sPw + l15 * 144 + 16 * l4);
  bf16x8 pa1 = *(const bf16x8*)(sPw + l15 * 144 + 16 * l4 + 64);
  #pragma unroll
  for (int db = 0; db < 8; ++db) {
    int row = db * 16 + l15;
    const char* vb = &sVt[row * 128];
    bf16x8 b0 = *(const bf16x8*)&vb[(16 * l4) ^ ((row & 7) << 4)];
    bf16x8 b1 = *(const bf16x8*)&vb[(64 + 16 * l4) ^ ((row & 7) << 4)];
    accO[db] = __builtin_amdgcn_mfma_f32_16x16x32_bf16(pa0, b0, accO[db], 0, 0, 0);
    accO[db] = __builtin_amdgcn_mfma_f32_16x16x32_bf16(pa1, b1, accO[db], 0, 0, 0);
  }
}

// grid: (16 pairs, B*H); block 256 = 4 waves. Pair p handles q-tiles p and 31-p.
__global__ __launch_bounds__(256, 2)
void k_attn(const u16* __restrict__ Q, const u16* __restrict__ Kg,
            const u16* __restrict__ Vt, u16* __restrict__ O) {
  __shared__ alignas(16) char sK[64 * 256];    // [64 k][128 d] bf16, XOR-swizzled 256B rows
  __shared__ alignas(16) char sVt[128 * 128];  // [128 d][64 k] bf16, XOR-swizzled 128B rows
  __shared__ alignas(16) char sP[4 * 2304];    // per-wave P [16 q][72] bf16
  const int tid = threadIdx.x, wid = tid >> 6, lane = tid & 63;
  const int l15 = lane & 15, l4 = lane >> 4;
  const int p = blockIdx.x;
  const int bh = blockIdx.y;
  const int b = bh >> 4, h = bh & 15;
  const int tA = p, tB = 31 - p;
  const u16* Qp = Q + ((size_t)bh << 18);
  const char* Kp = (const char*)(Kg + ((size_t)bh << 18));
  const char* Vtp = (const char*)(Vt + ((size_t)bh << 18));
  const int q0A = tA * 64 + wid * 16;
  const int q0B = tB * 64 + wid * 16;

  bf16x8 aqA[4], aqB[4];
  #pragma unroll
  for (int kk = 0; kk < 4; ++kk) {
    aqA[kk] = *(const bf16x8*)(Qp + (size_t)(q0A + l15) * DH + kk * 32 + 8 * l4);
    aqB[kk] = *(const bf16x8*)(Qp + (size_t)(q0B + l15) * DH + kk * 32 + 8 * l4);
  }

  f32x4 accA[8], accB[8];
  #pragma unroll
  for (int i = 0; i < 8; ++i) { accA[i] = (f32x4){0.f,0.f,0.f,0.f}; accB[i] = (f32x4){0.f,0.f,0.f,0.f}; }
  float mA[4] = {-1e30f,-1e30f,-1e30f,-1e30f}, mB[4] = {-1e30f,-1e30f,-1e30f,-1e30f};
  float seA[4] = {0.f,0.f,0.f,0.f}, seB[4] = {0.f,0.f,0.f,0.f};

  char* sPw = sP + wid * 2304;
  const int nt = tB + 1;
  for (int t = 0; t < nt; ++t) {
    const int kb = t << 6;
    __syncthreads();
    #pragma unroll
    for (int it = 0; it < 4; ++it) {
      int o = it * 4096 + tid * 16;
      int row = o >> 8, cb = o & 255;
      int scb = cb ^ ((row & 7) << 4);
      gload_lds16(Kp + (size_t)(kb + row) * 256 + scb, &sK[it * 4096 + wid * 1024]);
    }
    #pragma unroll
    for (int it = 0; it < 4; ++it) {
      int o = it * 4096 + tid * 16;
      int row = o >> 7, cb = o & 127;
      int scb = cb ^ ((row & 7) << 4);
      gload_lds16(Vtp + (size_t)row * (SEQ * 2) + kb * 2 + scb, &sVt[it * 4096 + wid * 1024]);
    }
    __syncthreads();

    attn_tile(sK, sVt, sPw, aqB, accB, mB, seB, q0B, kb, t == tB, l15, l4);
    if (t <= tA)
      attn_tile(sK, sVt, sPw, aqA, accA, mA, seA, q0A, kb, t == tA, l15, l4);
  }

  #pragma unroll
  for (int db = 0; db < 8; ++db) {
    #pragma unroll
    for (int j = 0; j < 4; ++j) {
      int d = db * 16 + l15;
      int qA = q0A + l4 * 4 + j;
      int qB = q0B + l4 * 4 + j;
      O[(size_t)(b * SEQ + qA) * HID + h * DH + d] = f2bf(accA[db][j] / seA[j]);
      O[(size_t)(b * SEQ + qB) * HID + h * DH + d] = f2bf(accB[db][j] / seB[j]);
    }
  }
}

extern "C" void kernel_launch(void* const* d_in, const int* in_sizes, int n_in,
                              void* d_out, int out_size, void* d_ws, size_t ws_size,
                              hipStream_t stream) {
  (void)in_sizes; (void)n_in; (void)out_size; (void)ws_size;
  const float* x = (const float*)d_in[0];
  const float* Wqkv = (const float*)d_in[1];
  const float* Wout = (const float*)d_in[2];
  float* out = (float*)d_out;
  char* ws = (char*)d_ws;

  u16* xb  = (u16*)(ws);                                   // 16 MB [4096][2048] bf16 (also attn O)
  u16* wqb = (u16*)(ws + (size_t)16777216);                // 24 MB [6144][2048] bf16
  u16* Vt  = wqb;                                          // aliases wqb AFTER gemm0 (16 MB)
  u16* wob = (u16*)(ws + (size_t)16777216 + 25165824);     // 8 MB  [2048][2048] bf16
  u16* Qr  = (u16*)(ws + (size_t)50331648);                // 16 MB each (8388608 u16 elements)
  u16* Kr  = Qr + (size_t)8388608;
  u16* Vr  = Kr + (size_t)8388608;
  u16* Ob  = xb;

  k_cvt<<<dim3(1024), dim3(256), 0, stream>>>(x, xb, (NB * SEQ * HID) / 4);
  k_cvt<<<dim3(1024), dim3(256), 0, stream>>>(Wqkv, wqb, (3 * HID * HID) / 4);
  k_cvt<<<dim3(1024), dim3(256), 0, stream>>>(Wout, wob, (HID * HID) / 4);

  k_gemm<0><<<dim3(48, 32), dim3(256), 0, stream>>>(xb, wqb, nullptr, Qr, Kr, Vr, 3 * HID, HID);

  k_vtr<<<dim3(SEQ / 64, DH / 64, NB * NH), dim3(256), 0, stream>>>(Vr, Vt);
  k_nrope<<<dim3((NB * NH * SEQ) / 4), dim3(256), 0, stream>>>(Qr);
  k_nrope<<<dim3((NB * NH * SEQ) / 4), dim3(256), 0, stream>>>(Kr);

  k_attn<<<dim3(16, NB * NH), dim3(256), 0, stream>>>(Qr, Kr, Vt, Ob);

  k_gemm<1><<<dim3(16, 32), dim3(256), 0, stream>>>(Ob, wob, out, nullptr, nullptr, nullptr, HID, HID);
}

// Round 4
// 316.434 us; speedup vs baseline: 1.3610x; 1.3557x over previous
//
#include <hip/hip_runtime.h>
#include <stdint.h>
#include <math.h>

typedef unsigned short u16;
typedef unsigned int u32;
typedef __attribute__((ext_vector_type(8))) short bf16x8;
typedef __attribute__((ext_vector_type(4))) float f32x4;

#define SEQ 2048
#define HID 2048
#define NH  16
#define DH  128
#define NB  2

typedef __attribute__((address_space(1))) const u32 gu32;
typedef __attribute__((address_space(3))) u32 lu32;

__device__ __forceinline__ u16 f2bf(float f) {
  u32 u = __float_as_uint(f);
  return (u16)((u + 0x7fffu + ((u >> 16) & 1u)) >> 16);
}
__device__ __forceinline__ float bf2f(u16 h) { return __uint_as_float(((u32)h) << 16); }

__device__ __forceinline__ void gload_lds16(const void* g, void* l) {
  __builtin_amdgcn_global_load_lds((gu32*)g, (lu32*)l, 16, 0, 0);
}

// ---------------- fp32 -> bf16 convert ----------------
__global__ __launch_bounds__(256) void k_cvt(const float* __restrict__ src, u16* __restrict__ dst, int n4) {
  int i = blockIdx.x * 256 + threadIdx.x;
  int stride = gridDim.x * 256;
  for (; i < n4; i += stride) {
    float4 v = ((const float4*)src)[i];
    ushort4 o;
    o.x = f2bf(v.x); o.y = f2bf(v.y); o.z = f2bf(v.z); o.w = f2bf(v.w);
    ((ushort4*)dst)[i] = o;
  }
}

// ---------------- GEMM C = A * B^T  (A:[M,K], B:[N,K], bf16 in, fp32 acc) ----------------
template<int EPI>
__global__ __launch_bounds__(256)
void k_gemm(const u16* __restrict__ A, const u16* __restrict__ Bm,
            float* __restrict__ Cf, u16* __restrict__ Qr, u16* __restrict__ Kr, u16* __restrict__ Vr,
            int N, int K) {
  __shared__ alignas(16) char sA[128 * 128];
  __shared__ alignas(16) char sB[128 * 128];
  const int tid = threadIdx.x;
  const int wid = tid >> 6, lane = tid & 63;
  const int l15 = lane & 15, l4 = lane >> 4;
  const int m0 = blockIdx.y * 128, n0 = blockIdx.x * 128;
  const int wr = (wid >> 1) * 64, wc = (wid & 1) * 64;

  f32x4 acc[4][4];
  #pragma unroll
  for (int i = 0; i < 4; ++i)
    #pragma unroll
    for (int j = 0; j < 4; ++j)
      acc[i][j] = (f32x4){0.f, 0.f, 0.f, 0.f};

  const int nkt = K >> 6;
  for (int kt = 0; kt < nkt; ++kt) {
    const int k0 = kt << 6;
    __syncthreads();
    #pragma unroll
    for (int it = 0; it < 4; ++it) {
      int o = it * 4096 + tid * 16;
      int row = o >> 7, cb = o & 127;
      int scb = cb ^ ((row & 7) << 4);
      gload_lds16((const char*)A + ((size_t)(m0 + row) * K + k0) * 2 + scb, &sA[it * 4096 + wid * 1024]);
    }
    #pragma unroll
    for (int it = 0; it < 4; ++it) {
      int o = it * 4096 + tid * 16;
      int row = o >> 7, cb = o & 127;
      int scb = cb ^ ((row & 7) << 4);
      gload_lds16((const char*)Bm + ((size_t)(n0 + row) * K + k0) * 2 + scb, &sB[it * 4096 + wid * 1024]);
    }
    __syncthreads();
    #pragma unroll
    for (int kk = 0; kk < 2; ++kk) {
      bf16x8 av[4], bv[4];
      #pragma unroll
      for (int mi = 0; mi < 4; ++mi) {
        int row = wr + mi * 16 + l15;
        int colb = kk * 64 + 16 * l4;
        av[mi] = *(const bf16x8*)&sA[row * 128 + (colb ^ ((row & 7) << 4))];
      }
      #pragma unroll
      for (int ni = 0; ni < 4; ++ni) {
        int row = wc + ni * 16 + l15;
        int colb = kk * 64 + 16 * l4;
        bv[ni] = *(const bf16x8*)&sB[row * 128 + (colb ^ ((row & 7) << 4))];
      }
      #pragma unroll
      for (int mi = 0; mi < 4; ++mi)
        #pragma unroll
        for (int ni = 0; ni < 4; ++ni)
          acc[mi][ni] = __builtin_amdgcn_mfma_f32_16x16x32_bf16(av[mi], bv[ni], acc[mi][ni], 0, 0, 0);
    }
  }

  #pragma unroll
  for (int mi = 0; mi < 4; ++mi) {
    #pragma unroll
    for (int ni = 0; ni < 4; ++ni) {
      #pragma unroll
      for (int j = 0; j < 4; ++j) {
        int gm = m0 + wr + mi * 16 + l4 * 4 + j;
        int gn = n0 + wc + ni * 16 + l15;
        float v = acc[mi][ni][j];
        if (EPI == 0) {
          int b = gm >> 11, l = gm & 2047;
          int which = gn >> 11, hid = gn & 2047;
          int h = hid >> 7, d = hid & 127;
          u16* dst = (which == 0) ? Qr : ((which == 1) ? Kr : Vr);
          size_t idx = ((size_t)(b * NH + h) * SEQ + l) * DH + d;
          dst[idx] = f2bf(v);
        } else {
          Cf[(size_t)gm * N + gn] = v;
        }
      }
    }
  }
}

// ---------------- V transpose: Vr[bh][l][d] -> Vt[bh][d][l] ----------------
__global__ __launch_bounds__(256) void k_vtr(const u16* __restrict__ Vr, u16* __restrict__ Vt) {
  __shared__ u16 tile[64][72];
  const int k0 = blockIdx.x * 64, d0 = blockIdx.y * 64, bh = blockIdx.z;
  const u16* src = Vr + ((size_t)bh << 18);
  u16* dst = Vt + ((size_t)bh << 18);
  const int tid = threadIdx.x;
  #pragma unroll
  for (int it = 0; it < 2; ++it) {
    int e = it * 2048 + tid * 8;
    int r = e >> 6, c = e & 63;
    bf16x8 v = *(const bf16x8*)(src + (size_t)(k0 + r) * DH + d0 + c);
    *(bf16x8*)&tile[r][c] = v;
  }
  __syncthreads();
  #pragma unroll
  for (int it = 0; it < 2; ++it) {
    int e = it * 2048 + tid * 8;
    int rd = e >> 6, ck = e & 63;
    bf16x8 w;
    #pragma unroll
    for (int i = 0; i < 8; ++i) w[i] = (short)tile[ck + i][rd];
    *(bf16x8*)(dst + (size_t)(d0 + rd) * SEQ + k0 + ck) = w;
  }
}

// ---------------- RMSNorm + interleaved RoPE, in place on [B*H*L][128] bf16 ----------------
__global__ __launch_bounds__(256) void k_nrope(u16* __restrict__ T) {
  const int r = blockIdx.x * 4 + (threadIdx.x >> 6);
  const int lane = threadIdx.x & 63;
  u16* p = T + ((size_t)r << 7) + lane * 2;
  u32 pr = *(const u32*)p;
  float xe = bf2f((u16)(pr & 0xffffu));
  float xo = bf2f((u16)(pr >> 16));
  float ss = xe * xe + xo * xo;
  #pragma unroll
  for (int off = 1; off < 64; off <<= 1) ss += __shfl_xor(ss, off);
  float rinv = rsqrtf(ss * (1.f / 128.f) + 1e-5f);
  float e = xe * rinv, o = xo * rinv;
  int pos = r & (SEQ - 1);
  float freq = exp2f(-0.20762050593046014f * (float)lane);
  float ang = (float)pos * freq;
  float sn, cs;
  sincosf(ang, &sn, &cs);
  u32 outw = (u32)f2bf(o * cs - e * sn) | ((u32)f2bf(o * sn + e * cs) << 16);
  *(u32*)p = outw;
}

// ---------------- causal flash attention, paired q-tiles, double-buffered ----------------
#define PSTR 68   // u16 elements per P row (136 B)

__device__ __forceinline__ void attn_tile(const char* sK, const char* sVt, char* sPw,
                                          const bf16x8* aq, f32x4* accO, float* m_, float* se,
                                          int q0, int kb, bool diag, int l15, int l4) {
  const float scale = 0.08838834764831845f;  // 1/sqrt(128)
  f32x4 sacc[4];
  __builtin_amdgcn_s_setprio(1);
  #pragma unroll
  for (int sj = 0; sj < 4; ++sj) {
    sacc[sj] = (f32x4){0.f, 0.f, 0.f, 0.f};
    int row = sj * 16 + l15;
    #pragma unroll
    for (int kk = 0; kk < 4; ++kk) {
      int colb = kk * 64 + 16 * l4;
      bf16x8 bk = *(const bf16x8*)&sK[(row << 8) + (colb ^ ((row & 7) << 4))];
      sacc[sj] = __builtin_amdgcn_mfma_f32_16x16x32_bf16(aq[kk], bk, sacc[sj], 0, 0, 0);
    }
  }
  __builtin_amdgcn_s_setprio(0);
  float pvv[4][4], rm[4], rs[4], corr[4];
  #pragma unroll
  for (int j = 0; j < 4; ++j) {
    int qpos = q0 + l4 * 4 + j;
    float mx = -1e30f;
    #pragma unroll
    for (int sj = 0; sj < 4; ++sj) {
      float s = sacc[sj][j] * scale;
      if (diag) {
        int kpos = kb + sj * 16 + l15;
        s = (kpos > qpos) ? -1e30f : s;
      }
      pvv[sj][j] = s;
      mx = fmaxf(mx, s);
    }
    rm[j] = mx;
  }
  #pragma unroll
  for (int off = 1; off < 16; off <<= 1) {
    #pragma unroll
    for (int j = 0; j < 4; ++j) rm[j] = fmaxf(rm[j], __shfl_xor(rm[j], off));
  }
  #pragma unroll
  for (int j = 0; j < 4; ++j) {
    float mn = fmaxf(m_[j], rm[j]);
    corr[j] = __expf(m_[j] - mn);
    m_[j] = mn;
    float sum = 0.f;
    #pragma unroll
    for (int sj = 0; sj < 4; ++sj) { float pe = __expf(pvv[sj][j] - mn); pvv[sj][j] = pe; sum += pe; }
    rs[j] = sum;
  }
  #pragma unroll
  for (int off = 1; off < 16; off <<= 1) {
    #pragma unroll
    for (int j = 0; j < 4; ++j) rs[j] += __shfl_xor(rs[j], off);
  }
  #pragma unroll
  for (int j = 0; j < 4; ++j) se[j] = se[j] * corr[j] + rs[j];
  #pragma unroll
  for (int db = 0; db < 8; ++db) {
    f32x4 a = accO[db];
    #pragma unroll
    for (int j = 0; j < 4; ++j) a[j] *= corr[j];
    accO[db] = a;
  }
  {
    u16* Pw = (u16*)sPw;
    #pragma unroll
    for (int sj = 0; sj < 4; ++sj)
      #pragma unroll
      for (int j = 0; j < 4; ++j)
        Pw[(l4 * 4 + j) * PSTR + sj * 16 + l15] = f2bf(pvv[sj][j]);
  }
  bf16x8 pa0 = *(const bf16x8*)(sPw + l15 * (PSTR * 2) + 16 * l4);
  bf16x8 pa1 = *(const bf16x8*)(sPw + l15 * (PSTR * 2) + 16 * l4 + 64);
  __builtin_amdgcn_s_setprio(1);
  #pragma unroll
  for (int db = 0; db < 8; ++db) {
    int row = db * 16 + l15;
    const char* vb = &sVt[row * 128];
    bf16x8 b0 = *(const bf16x8*)&vb[(16 * l4) ^ ((row & 7) << 4)];
    bf16x8 b1 = *(const bf16x8*)&vb[(64 + 16 * l4) ^ ((row & 7) << 4)];
    accO[db] = __builtin_amdgcn_mfma_f32_16x16x32_bf16(pa0, b0, accO[db], 0, 0, 0);
    accO[db] = __builtin_amdgcn_mfma_f32_16x16x32_bf16(pa1, b1, accO[db], 0, 0, 0);
  }
  __builtin_amdgcn_s_setprio(0);
}

__device__ __forceinline__ void stage_kv(const char* Kp, const char* Vtp, int kb,
                                         char* bK, char* bV, int tid, int wid) {
  #pragma unroll
  for (int it = 0; it < 4; ++it) {
    int o = it * 4096 + tid * 16;
    int row = o >> 8, cb = o & 255;
    int scb = cb ^ ((row & 7) << 4);
    gload_lds16(Kp + (size_t)(kb + row) * 256 + scb, &bK[it * 4096 + wid * 1024]);
  }
  #pragma unroll
  for (int it = 0; it < 4; ++it) {
    int o = it * 4096 + tid * 16;
    int row = o >> 7, cb = o & 127;
    int scb = cb ^ ((row & 7) << 4);
    gload_lds16(Vtp + (size_t)row * (SEQ * 2) + kb * 2 + scb, &bV[it * 4096 + wid * 1024]);
  }
}

// grid: 512 blocks (1-D, XCD-remapped); block 256 = 4 waves. Pair p: q-tiles p and 31-p.
__global__ __launch_bounds__(256, 2)
void k_attn(const u16* __restrict__ Q, const u16* __restrict__ Kg,
            const u16* __restrict__ Vt, u16* __restrict__ O) {
  __shared__ alignas(16) char sK0[64 * 256];
  __shared__ alignas(16) char sK1[64 * 256];
  __shared__ alignas(16) char sV0[128 * 128];
  __shared__ alignas(16) char sV1[128 * 128];
  __shared__ alignas(16) char sP[4 * 16 * PSTR * 2];
  const int tid = threadIdx.x, wid = tid >> 6, lane = tid & 63;
  const int l15 = lane & 15, l4 = lane >> 4;
  // XCD-aware remap: all 16 pair-blocks of one head land on one XCD (xcd = id % 8).
  const int i = blockIdx.x;
  const int xcd = i & 7, slot = i >> 3;
  const int p = slot & 15;
  const int bh = xcd + 8 * (slot >> 4);
  const int b = bh >> 4, h = bh & 15;
  const int tA = p, tB = 31 - p;
  const u16* Qp = Q + ((size_t)bh << 18);
  const char* Kp = (const char*)(Kg + ((size_t)bh << 18));
  const char* Vtp = (const char*)(Vt + ((size_t)bh << 18));
  const int q0A = tA * 64 + wid * 16;
  const int q0B = tB * 64 + wid * 16;

  bf16x8 aqA[4], aqB[4];
  #pragma unroll
  for (int kk = 0; kk < 4; ++kk) {
    aqA[kk] = *(const bf16x8*)(Qp + (size_t)(q0A + l15) * DH + kk * 32 + 8 * l4);
    aqB[kk] = *(const bf16x8*)(Qp + (size_t)(q0B + l15) * DH + kk * 32 + 8 * l4);
  }

  f32x4 accA[8], accB[8];
  #pragma unroll
  for (int i2 = 0; i2 < 8; ++i2) { accA[i2] = (f32x4){0.f,0.f,0.f,0.f}; accB[i2] = (f32x4){0.f,0.f,0.f,0.f}; }
  float mA[4] = {-1e30f,-1e30f,-1e30f,-1e30f}, mB[4] = {-1e30f,-1e30f,-1e30f,-1e30f};
  float seA[4] = {0.f,0.f,0.f,0.f}, seB[4] = {0.f,0.f,0.f,0.f};

  char* sPw = sP + wid * (16 * PSTR * 2);
  const int nt = tB + 1;

  stage_kv(Kp, Vtp, 0, sK0, sV0, tid, wid);
  for (int t = 0; t < nt; ++t) {
    char* bK = (t & 1) ? sK1 : sK0;
    char* bV = (t & 1) ? sV1 : sV0;
    if (t + 1 < nt) {
      stage_kv(Kp, Vtp, (t + 1) << 6, (t & 1) ? sK0 : sK1, (t & 1) ? sV0 : sV1, tid, wid);
      asm volatile("s_waitcnt vmcnt(8)" ::: "memory");
    } else {
      asm volatile("s_waitcnt vmcnt(0)" ::: "memory");
    }
    __builtin_amdgcn_sched_barrier(0);
    __builtin_amdgcn_s_barrier();

    const int kb = t << 6;
    attn_tile(bK, bV, sPw, aqB, accB, mB, seB, q0B, kb, t == tB, l15, l4);
    if (t <= tA)
      attn_tile(bK, bV, sPw, aqA, accA, mA, seA, q0A, kb, t == tA, l15, l4);

    __builtin_amdgcn_s_barrier();
  }

  #pragma unroll
  for (int db = 0; db < 8; ++db) {
    #pragma unroll
    for (int j = 0; j < 4; ++j) {
      int d = db * 16 + l15;
      int qA = q0A + l4 * 4 + j;
      int qB = q0B + l4 * 4 + j;
      O[(size_t)(b * SEQ + qA) * HID + h * DH + d] = f2bf(accA[db][j] / seA[j]);
      O[(size_t)(b * SEQ + qB) * HID + h * DH + d] = f2bf(accB[db][j] / seB[j]);
    }
  }
}

extern "C" void kernel_launch(void* const* d_in, const int* in_sizes, int n_in,
                              void* d_out, int out_size, void* d_ws, size_t ws_size,
                              hipStream_t stream) {
  (void)in_sizes; (void)n_in; (void)out_size; (void)ws_size;
  const float* x = (const float*)d_in[0];
  const float* Wqkv = (const float*)d_in[1];
  const float* Wout = (const float*)d_in[2];
  float* out = (float*)d_out;
  char* ws = (char*)d_ws;

  u16* xb  = (u16*)(ws);                                   // 16 MB [4096][2048] bf16 (also attn O)
  u16* wqb = (u16*)(ws + (size_t)16777216);                // 24 MB [6144][2048] bf16
  u16* Vt  = wqb;                                          // aliases wqb AFTER gemm0 (16 MB)
  u16* wob = (u16*)(ws + (size_t)16777216 + 25165824);     // 8 MB  [2048][2048] bf16
  u16* Qr  = (u16*)(ws + (size_t)50331648);                // 16 MB each (8388608 u16 elements)
  u16* Kr  = Qr + (size_t)8388608;
  u16* Vr  = Kr + (size_t)8388608;
  u16* Ob  = xb;

  k_cvt<<<dim3(1024), dim3(256), 0, stream>>>(x, xb, (NB * SEQ * HID) / 4);
  k_cvt<<<dim3(1024), dim3(256), 0, stream>>>(Wqkv, wqb, (3 * HID * HID) / 4);
  k_cvt<<<dim3(1024), dim3(256), 0, stream>>>(Wout, wob, (HID * HID) / 4);

  k_gemm<0><<<dim3(48, 32), dim3(256), 0, stream>>>(xb, wqb, nullptr, Qr, Kr, Vr, 3 * HID, HID);

  k_vtr<<<dim3(SEQ / 64, DH / 64, NB * NH), dim3(256), 0, stream>>>(Vr, Vt);
  k_nrope<<<dim3((NB * NH * SEQ) / 4), dim3(256), 0, stream>>>(Qr);
  k_nrope<<<dim3((NB * NH * SEQ) / 4), dim3(256), 0, stream>>>(Kr);

  k_attn<<<dim3(512), dim3(256), 0, stream>>>(Qr, Kr, Vt, Ob);

  k_gemm<1><<<dim3(16, 32), dim3(256), 0, stream>>>(Ob, wob, out, nullptr, nullptr, nullptr, HID, HID);
}